// Round 1
// baseline (798.321 us; speedup 1.0000x reference)
//
#include <hip/hip_runtime.h>
#include <hip/hip_bf16.h>

typedef __attribute__((ext_vector_type(4))) float f32x4;
typedef __attribute__((ext_vector_type(4))) unsigned int u32x4;
typedef __attribute__((ext_vector_type(2))) unsigned int u32x2;

// Problem constants
static constexpr int Bb = 64;
static constexpr int Tt = 2048;
static constexpr int Ee = 1024;
static constexpr int Hh = 1024;
static constexpr int Mtot = Bb * Tt;        // 131072
static constexpr int ATTN_N = Bb * Ee;      // 65536
static constexpr int PROB_N = Bb * Tt;      // 131072

__device__ inline unsigned short f2bf(float f) {
    __hip_bfloat16 h = __float2bfloat16(f);  // RNE
    return __builtin_bit_cast(unsigned short, h);
}

// ---------------------------------------------------------------------------
// K0a: W_enc [E][H] fp32  ->  W16T [H][E] bf16 (transposed so GEMM B-frags are
// k-contiguous in LDS)
// ---------------------------------------------------------------------------
__global__ void wtrans_kernel(const float* __restrict__ w_enc,
                              unsigned short* __restrict__ w16t) {
    __shared__ float tile[32][33];
    const int bx = blockIdx.x & 31;   // h tile
    const int by = blockIdx.x >> 5;   // e tile
    const int tx = threadIdx.x & 31;
    const int ty = threadIdx.x >> 5;  // 0..7
#pragma unroll
    for (int j = 0; j < 4; ++j) {
        int e = by * 32 + ty + j * 8;
        int h = bx * 32 + tx;
        tile[ty + j * 8][tx] = w_enc[e * Hh + h];
    }
    __syncthreads();
#pragma unroll
    for (int j = 0; j < 4; ++j) {
        int h = bx * 32 + ty + j * 8;
        int e = by * 32 + tx;
        w16t[h * Ee + e] = f2bf(tile[tx][ty + j * 8]);
    }
}

// ---------------------------------------------------------------------------
// K0b: ddec[b][h] = dec[b]·W_dec[:,h] + b_dec[h] + b_enc[h]   (fp32 exact)
// ---------------------------------------------------------------------------
__global__ void ddec_kernel(const float* __restrict__ dec,
                            const float* __restrict__ w_dec,
                            const float* __restrict__ b_dec,
                            const float* __restrict__ b_enc,
                            float* __restrict__ ddec) {
    const int b = blockIdx.y;
    const int h = blockIdx.x * 256 + threadIdx.x;
    float acc = b_dec[h] + b_enc[h];
    const float* dr = dec + b * Ee;
#pragma unroll 4
    for (int e = 0; e < Ee; ++e) {
        acc += dr[e] * w_dec[e * Hh + h];
    }
    ddec[b * Hh + h] = acc;
}

// ---------------------------------------------------------------------------
// K1: fused  scores_partial[b,t] += sum_h tanh(enc·W_enc + ddec) * W_out[h]
// 128x128 tile, BK=64, 4 waves (each 64x64), mfma_f32_16x16x32_bf16.
// A (enc fp32) converted to bf16 during reg-staging; B from pre-converted
// transposed W16T. XOR-swizzled LDS for conflict-free ds_read_b128.
// ---------------------------------------------------------------------------
__global__ __launch_bounds__(256, 2) void gemm_score_kernel(
    const float* __restrict__ enc, const unsigned short* __restrict__ w16t,
    const float* __restrict__ ddec, const float* __restrict__ w_out,
    float* __restrict__ scores) {
    __shared__ unsigned short As[128 * 64];
    __shared__ unsigned short Bs[128 * 64];

    const int tid = threadIdx.x;
    const int lane = tid & 63;
    const int wid = tid >> 6;          // 0..3
    const int wm = wid >> 1;           // 0..1
    const int wn = wid & 1;            // 0..1
    const int lr = lane & 15;
    const int lg = lane >> 4;          // 0..3

    const int ntile = blockIdx.x;      // 0..7  (fastest -> A-panel L2 reuse)
    const int mtile = blockIdx.y;      // 0..1023
    const int m0 = mtile * 128;
    const int n0 = ntile * 128;
    const int bidx = m0 >> 11;         // /T : whole tile in one batch row

    // staging maps
    const int arow = tid >> 4;          // 0..15 (+16*ci)
    const int acol = (tid & 15) * 4;    // float4 column
    const int brow = tid >> 3;          // 0..31 (+32*ci)
    const int bcol = (tid & 7) * 8;     // 8 bf16 (16B) chunk

    f32x4 areg[8];
    u32x4 breg[4];

    auto loadA = [&](int kt) {
        const float* src = enc + (size_t)m0 * Ee + kt * 64 + acol;
#pragma unroll
        for (int ci = 0; ci < 8; ++ci)
            areg[ci] = *reinterpret_cast<const f32x4*>(src + (size_t)(arow + 16 * ci) * Ee);
    };
    auto loadB = [&](int kt) {
        const unsigned short* src = w16t + (size_t)n0 * Ee + kt * 64 + bcol;
#pragma unroll
        for (int ci = 0; ci < 4; ++ci)
            breg[ci] = *reinterpret_cast<const u32x4*>(src + (size_t)(brow + 32 * ci) * Ee);
    };
    auto storeA = [&]() {
#pragma unroll
        for (int ci = 0; ci < 8; ++ci) {
            int r = arow + 16 * ci;
            int off = r * 128 + ((acol * 2) ^ ((r & 7) << 4));
            unsigned int lo = (unsigned)f2bf(areg[ci].x) | ((unsigned)f2bf(areg[ci].y) << 16);
            unsigned int hi = (unsigned)f2bf(areg[ci].z) | ((unsigned)f2bf(areg[ci].w) << 16);
            u32x2 w; w.x = lo; w.y = hi;
            *reinterpret_cast<u32x2*>((char*)As + off) = w;
        }
    };
    auto storeB = [&]() {
#pragma unroll
        for (int ci = 0; ci < 4; ++ci) {
            int r = brow + 32 * ci;
            int off = r * 128 + ((bcol * 2) ^ ((r & 7) << 4));
            *reinterpret_cast<u32x4*>((char*)Bs + off) = breg[ci];
        }
    };

    // accumulators init with ddec (same value for every row of a column)
    f32x4 acc[4][4];
#pragma unroll
    for (int ni = 0; ni < 4; ++ni) {
        float dv = ddec[bidx * Hh + n0 + wn * 64 + ni * 16 + lr];
#pragma unroll
        for (int mi = 0; mi < 4; ++mi) {
            acc[mi][ni].x = dv; acc[mi][ni].y = dv;
            acc[mi][ni].z = dv; acc[mi][ni].w = dv;
        }
    }

    loadA(0);
    loadB(0);

    for (int kt = 0; kt < Ee / 64; ++kt) {
        __syncthreads();          // previous tile fully consumed
        storeA();
        storeB();
        __syncthreads();          // tile visible
        if (kt < Ee / 64 - 1) {   // prefetch next tile into regs under compute
            loadA(kt + 1);
            loadB(kt + 1);
        }
#pragma unroll
        for (int kh = 0; kh < 2; ++kh) {
            const int kb = (kh * 32 + 8 * lg) * 2;   // byte offset of k-chunk
            u32x4 af[4], bf[4];
#pragma unroll
            for (int mi = 0; mi < 4; ++mi) {
                int r = wm * 64 + mi * 16 + lr;
                af[mi] = *reinterpret_cast<const u32x4*>((char*)As + r * 128 + (kb ^ ((r & 7) << 4)));
            }
#pragma unroll
            for (int ni = 0; ni < 4; ++ni) {
                int r = wn * 64 + ni * 16 + lr;
                bf[ni] = *reinterpret_cast<const u32x4*>((char*)Bs + r * 128 + (kb ^ ((r & 7) << 4)));
            }
#pragma unroll
            for (int mi = 0; mi < 4; ++mi)
#pragma unroll
                for (int ni = 0; ni < 4; ++ni)
                    asm("v_mfma_f32_16x16x32_bf16 %0, %1, %2, %0"
                        : "+v"(acc[mi][ni])
                        : "v"(af[mi]), "v"(bf[ni]));
        }
    }

    // drain MFMA pipe before VALU reads of acc
    asm volatile("s_nop 7\n\ts_nop 7\n\ts_nop 7" ::: );

    float wout[4];
#pragma unroll
    for (int ni = 0; ni < 4; ++ni)
        wout[ni] = w_out[n0 + wn * 64 + ni * 16 + lr];

#pragma unroll
    for (int mi = 0; mi < 4; ++mi) {
#pragma unroll
        for (int i = 0; i < 4; ++i) {
            float s = 0.f;
#pragma unroll
            for (int ni = 0; ni < 4; ++ni) {
                float x = (i == 0) ? acc[mi][ni].x : (i == 1) ? acc[mi][ni].y
                           : (i == 2) ? acc[mi][ni].z : acc[mi][ni].w;
                // tanh(x) = 1 - 2/(e^{2x}+1)  (stable at +/-inf)
                float t = 1.f - 2.f / (__expf(2.f * x) + 1.f);
                s += t * wout[ni];
            }
            s += __shfl_xor(s, 1);
            s += __shfl_xor(s, 2);
            s += __shfl_xor(s, 4);
            s += __shfl_xor(s, 8);
            if (lr == 0) {
                int row = m0 + wm * 64 + mi * 16 + 4 * lg + i;
                atomicAdd(&scores[row], s);
            }
        }
    }
}

// ---------------------------------------------------------------------------
// K2: masked softmax over T per batch row, in place (scores -> probs).
// b_out cancels in softmax so it is never added.
// ---------------------------------------------------------------------------
__global__ __launch_bounds__(256) void softmax_kernel(float* __restrict__ sc,
                                                      const int* __restrict__ mask) {
    __shared__ float red[256];
    const int b = blockIdx.x;
    const int tid = threadIdx.x;
    float* row = sc + b * Tt;
    const int* mrow = mask + b * Tt;

    float v[8];
    float mx = -3.0e38f;
#pragma unroll
    for (int j = 0; j < 8; ++j) {
        int t = tid + j * 256;
        float s = row[t];
        v[j] = (mrow[t] == 0) ? -1.0e9f : s;
        mx = fmaxf(mx, v[j]);
    }
    red[tid] = mx;
    __syncthreads();
    for (int off = 128; off > 0; off >>= 1) {
        if (tid < off) red[tid] = fmaxf(red[tid], red[tid + off]);
        __syncthreads();
    }
    mx = red[0];
    __syncthreads();

    float p[8];
    float sum = 0.f;
#pragma unroll
    for (int j = 0; j < 8; ++j) {
        p[j] = __expf(v[j] - mx);   // masked -> exp(~-1e9) == 0 exactly
        sum += p[j];
    }
    red[tid] = sum;
    __syncthreads();
    for (int off = 128; off > 0; off >>= 1) {
        if (tid < off) red[tid] += red[tid + off];
        __syncthreads();
    }
    float inv = 1.f / red[0];
#pragma unroll
    for (int j = 0; j < 8; ++j)
        row[tid + j * 256] = p[j] * inv;
}

// ---------------------------------------------------------------------------
// K3: attn[b][e] = sum_t probs[b][t] * enc[b][t][e]   (memory bound)
// ---------------------------------------------------------------------------
__global__ __launch_bounds__(256) void attn_kernel(const float* __restrict__ enc,
                                                   const float* __restrict__ probs,
                                                   float* __restrict__ attn) {
    __shared__ float pr[128];
    const int b = blockIdx.y;
    const int tc = blockIdx.x;        // 0..15  t-chunk of 128
    const int tid = threadIdx.x;
    if (tid < 128) pr[tid] = probs[b * Tt + tc * 128 + tid];
    __syncthreads();

    const int e0 = tid * 4;
    f32x4 acc; acc.x = 0.f; acc.y = 0.f; acc.z = 0.f; acc.w = 0.f;
    const float* base = enc + (size_t)b * Tt * Ee + (size_t)tc * 128 * Ee + e0;
#pragma unroll 4
    for (int t = 0; t < 128; ++t) {
        f32x4 vv = *reinterpret_cast<const f32x4*>(base + (size_t)t * Ee);
        float pw = pr[t];
        acc.x += pw * vv.x; acc.y += pw * vv.y;
        acc.z += pw * vv.z; acc.w += pw * vv.w;
    }
    atomicAdd(&attn[b * Ee + e0 + 0], acc.x);
    atomicAdd(&attn[b * Ee + e0 + 1], acc.y);
    atomicAdd(&attn[b * Ee + e0 + 2], acc.z);
    atomicAdd(&attn[b * Ee + e0 + 3], acc.w);
}

// ---------------------------------------------------------------------------
extern "C" void kernel_launch(void* const* d_in, const int* in_sizes, int n_in,
                              void* d_out, int out_size, void* d_ws, size_t ws_size,
                              hipStream_t stream) {
    const float* enc      = (const float*)d_in[0];
    const float* dec      = (const float*)d_in[1];
    const int*   inp_mask = (const int*)d_in[2];
    const float* W_enc    = (const float*)d_in[3];
    const float* b_enc    = (const float*)d_in[4];
    const float* W_dec    = (const float*)d_in[5];
    const float* b_dec    = (const float*)d_in[6];
    const float* W_out    = (const float*)d_in[7];
    // b_out (d_in[8]) cancels in softmax and is otherwise unused.

    float* attn   = (float*)d_out;            // [64][1024]
    float* scores = (float*)d_out + ATTN_N;   // [64][2048], becomes probs

    unsigned short* w16t = (unsigned short*)d_ws;  // 2 MB bf16 W_enc^T
    // ddec [64][1024] fp32 lives temporarily in the attn region of d_out;
    // it is consumed by gemm_score_kernel, then the region is zeroed for K3.
    float* ddec = attn;

    // zero score accumulator
    hipMemsetAsync(scores, 0, (size_t)PROB_N * sizeof(float), stream);

    wtrans_kernel<<<dim3(1024), 256, 0, stream>>>(W_enc, w16t);
    ddec_kernel<<<dim3(4, 64), 256, 0, stream>>>(dec, W_dec, b_dec, b_enc, ddec);
    gemm_score_kernel<<<dim3(8, 1024), 256, 0, stream>>>(enc, w16t, ddec, W_out, scores);

    // attn region done serving as ddec; zero it for atomic accumulation
    hipMemsetAsync(attn, 0, (size_t)ATTN_N * sizeof(float), stream);

    softmax_kernel<<<dim3(64), 256, 0, stream>>>(scores, inp_mask);
    attn_kernel<<<dim3(16, 64), 256, 0, stream>>>(enc, scores, attn);
}

// Round 3
// 675.344 us; speedup vs baseline: 1.1821x; 1.1821x over previous
//
#include <hip/hip_runtime.h>
#include <hip/hip_bf16.h>

typedef __attribute__((ext_vector_type(4))) float f32x4;
typedef __attribute__((ext_vector_type(4))) unsigned int u32x4;
typedef __attribute__((ext_vector_type(2))) unsigned int u32x2;

// Problem constants
static constexpr int Bb = 64;
static constexpr int Tt = 2048;
static constexpr int Ee = 1024;
static constexpr int Hh = 1024;
static constexpr int ATTN_N = Bb * Ee;      // 65536
static constexpr int PROB_N = Bb * Tt;      // 131072

__device__ inline unsigned short f2bf(float f) {
    __hip_bfloat16 h = __float2bfloat16(f);  // RNE
    return __builtin_bit_cast(unsigned short, h);
}

// ---------------------------------------------------------------------------
// K0a: W_enc [E][H] fp32  ->  W16T [H][E] bf16 (transposed so GEMM B-frags are
// k-contiguous in LDS)
// ---------------------------------------------------------------------------
__global__ void wtrans_kernel(const float* __restrict__ w_enc,
                              unsigned short* __restrict__ w16t) {
    __shared__ float tile[32][33];
    const int bx = blockIdx.x & 31;   // h tile
    const int by = blockIdx.x >> 5;   // e tile
    const int tx = threadIdx.x & 31;
    const int ty = threadIdx.x >> 5;  // 0..7
#pragma unroll
    for (int j = 0; j < 4; ++j) {
        int e = by * 32 + ty + j * 8;
        int h = bx * 32 + tx;
        tile[ty + j * 8][tx] = w_enc[e * Hh + h];
    }
    __syncthreads();
#pragma unroll
    for (int j = 0; j < 4; ++j) {
        int h = bx * 32 + ty + j * 8;
        int e = by * 32 + tx;
        w16t[h * Ee + e] = f2bf(tile[tx][ty + j * 8]);
    }
}

// ---------------------------------------------------------------------------
// K0b: ddec[b][h] = dec[b]·W_dec[:,h] + b_dec[h] + b_enc[h]   (fp32 exact)
// ---------------------------------------------------------------------------
__global__ void ddec_kernel(const float* __restrict__ dec,
                            const float* __restrict__ w_dec,
                            const float* __restrict__ b_dec,
                            const float* __restrict__ b_enc,
                            float* __restrict__ ddec) {
    const int b = blockIdx.y;
    const int h = blockIdx.x * 256 + threadIdx.x;
    float acc = b_dec[h] + b_enc[h];
    const float* dr = dec + b * Ee;
#pragma unroll 4
    for (int e = 0; e < Ee; ++e) {
        acc += dr[e] * w_dec[e * Hh + h];
    }
    ddec[b * Hh + h] = acc;
}

// ---------------------------------------------------------------------------
// K1: fused  scores[b,t] += sum_h tanh(enc·W_enc + ddec) * W_out[h]
// 128x256 tile, BK=64, 8 waves (2M x 4N, each 64x64), mfma_f32_16x16x32_bf16.
// A (enc fp32) converted to bf16 during reg-staging; B from pre-converted
// transposed W16T. XOR-swizzled LDS for conflict-free ds_read_b128.
// XCD-aware block swizzle: the 4 n-tiles sharing an A-panel are consecutive
// slots on the SAME XCD -> A-panel served from that XCD's L2 (T1).
// ---------------------------------------------------------------------------
__global__ __launch_bounds__(512, 2) void gemm_score_kernel(
    const float* __restrict__ enc, const unsigned short* __restrict__ w16t,
    const float* __restrict__ ddec, const float* __restrict__ w_out,
    float* __restrict__ scores) {
    __shared__ unsigned short As[128 * 64];
    __shared__ unsigned short Bs[256 * 64];

    const int tid = threadIdx.x;
    const int lane = tid & 63;
    const int wid = tid >> 6;          // 0..7
    const int wm = wid >> 2;           // 0..1
    const int wn = wid & 3;            // 0..3
    const int lr = lane & 15;
    const int lg = lane >> 4;          // 0..3

    // XCD-aware swizzle (8 XCDs, round-robin b->XCD b%8).
    // 1024 m-tiles x 4 n-tiles. Each XCD owns 128 contiguous m-tiles; the
    // 4 sibling n-tiles of an m-tile are consecutive slots on that XCD.
    const int g = blockIdx.x;
    const int xcd = g & 7;
    const int slot = g >> 3;           // 0..511
    const int ntile = slot & 3;        // 0..3
    const int mtile = xcd * 128 + (slot >> 2);  // 0..1023
    const int m0 = mtile * 128;
    const int n0 = ntile * 256;
    const int bidx = m0 >> 11;         // /T : whole tile in one batch row

    // staging maps (512 threads)
    const int arow = tid >> 4;          // 0..31 (+32*ci, 4 chunks)
    const int acol = (tid & 15) * 4;    // float4 column
    const int brow = tid >> 3;          // 0..63 (+64*ci, 4 chunks)
    const int bcol = (tid & 7) * 8;     // 8 bf16 (16B) chunk

    f32x4 areg[4];
    u32x4 breg[4];

    auto loadA = [&](int kt) {
        const float* src = enc + (size_t)m0 * Ee + kt * 64 + acol;
#pragma unroll
        for (int ci = 0; ci < 4; ++ci)
            areg[ci] = *reinterpret_cast<const f32x4*>(src + (size_t)(arow + 32 * ci) * Ee);
    };
    auto loadB = [&](int kt) {
        const unsigned short* src = w16t + (size_t)n0 * Ee + kt * 64 + bcol;
#pragma unroll
        for (int ci = 0; ci < 4; ++ci)
            breg[ci] = *reinterpret_cast<const u32x4*>(src + (size_t)(brow + 64 * ci) * Ee);
    };
    auto storeA = [&]() {
#pragma unroll
        for (int ci = 0; ci < 4; ++ci) {
            int r = arow + 32 * ci;
            int off = r * 128 + ((acol * 2) ^ ((r & 7) << 4));
            unsigned int lo = (unsigned)f2bf(areg[ci].x) | ((unsigned)f2bf(areg[ci].y) << 16);
            unsigned int hi = (unsigned)f2bf(areg[ci].z) | ((unsigned)f2bf(areg[ci].w) << 16);
            u32x2 w; w.x = lo; w.y = hi;
            *reinterpret_cast<u32x2*>((char*)As + off) = w;
        }
    };
    auto storeB = [&]() {
#pragma unroll
        for (int ci = 0; ci < 4; ++ci) {
            int r = brow + 64 * ci;
            int off = r * 128 + ((bcol * 2) ^ ((r & 7) << 4));
            *reinterpret_cast<u32x4*>((char*)Bs + off) = breg[ci];
        }
    };

    // accumulators init with ddec (same value for every row of a column)
    f32x4 acc[4][4];
#pragma unroll
    for (int ni = 0; ni < 4; ++ni) {
        float dv = ddec[bidx * Hh + n0 + wn * 64 + ni * 16 + lr];
#pragma unroll
        for (int mi = 0; mi < 4; ++mi) {
            acc[mi][ni].x = dv; acc[mi][ni].y = dv;
            acc[mi][ni].z = dv; acc[mi][ni].w = dv;
        }
    }

    loadA(0);
    loadB(0);

    for (int kt = 0; kt < Ee / 64; ++kt) {
        __syncthreads();          // previous tile fully consumed
        storeA();
        storeB();
        __syncthreads();          // tile visible
        if (kt < Ee / 64 - 1) {   // prefetch next tile into regs under compute
            loadA(kt + 1);
            loadB(kt + 1);
        }
#pragma unroll
        for (int kh = 0; kh < 2; ++kh) {
            const int kb = (kh * 32 + 8 * lg) * 2;   // byte offset of k-chunk
            u32x4 af[4], bf[4];
#pragma unroll
            for (int mi = 0; mi < 4; ++mi) {
                int r = wm * 64 + mi * 16 + lr;
                af[mi] = *reinterpret_cast<const u32x4*>((char*)As + r * 128 + (kb ^ ((r & 7) << 4)));
            }
#pragma unroll
            for (int ni = 0; ni < 4; ++ni) {
                int r = wn * 64 + ni * 16 + lr;
                bf[ni] = *reinterpret_cast<const u32x4*>((char*)Bs + r * 128 + (kb ^ ((r & 7) << 4)));
            }
#pragma unroll
            for (int mi = 0; mi < 4; ++mi)
#pragma unroll
                for (int ni = 0; ni < 4; ++ni)
                    asm("v_mfma_f32_16x16x32_bf16 %0, %1, %2, %0"
                        : "+v"(acc[mi][ni])
                        : "v"(af[mi]), "v"(bf[ni]));
        }
    }

    // drain MFMA pipe before VALU reads of acc
    asm volatile("s_nop 7\n\ts_nop 7\n\ts_nop 7" ::: );

    float wout[4];
#pragma unroll
    for (int ni = 0; ni < 4; ++ni)
        wout[ni] = w_out[n0 + wn * 64 + ni * 16 + lr];

#pragma unroll
    for (int mi = 0; mi < 4; ++mi) {
#pragma unroll
        for (int i = 0; i < 4; ++i) {
            float s = 0.f;
#pragma unroll
            for (int ni = 0; ni < 4; ++ni) {
                float x = (i == 0) ? acc[mi][ni].x : (i == 1) ? acc[mi][ni].y
                           : (i == 2) ? acc[mi][ni].z : acc[mi][ni].w;
                // tanh(x) = 1 - 2/(e^{2x}+1)  (stable at +/-inf)
                float t = 1.f - 2.f / (__expf(2.f * x) + 1.f);
                s += t * wout[ni];
            }
            s += __shfl_xor(s, 1);
            s += __shfl_xor(s, 2);
            s += __shfl_xor(s, 4);
            s += __shfl_xor(s, 8);
            if (lr == 0) {
                int row = m0 + wm * 64 + mi * 16 + 4 * lg + i;
                atomicAdd(&scores[row], s);
            }
        }
    }
}

// ---------------------------------------------------------------------------
// K2: masked softmax over T per batch row, in place (scores -> probs).
// b_out cancels in softmax so it is never added.
// ---------------------------------------------------------------------------
__global__ __launch_bounds__(256) void softmax_kernel(float* __restrict__ sc,
                                                      const int* __restrict__ mask) {
    __shared__ float red[256];
    const int b = blockIdx.x;
    const int tid = threadIdx.x;
    float* row = sc + b * Tt;
    const int* mrow = mask + b * Tt;

    float v[8];
    float mx = -3.0e38f;
#pragma unroll
    for (int j = 0; j < 8; ++j) {
        int t = tid + j * 256;
        float s = row[t];
        v[j] = (mrow[t] == 0) ? -1.0e9f : s;
        mx = fmaxf(mx, v[j]);
    }
    red[tid] = mx;
    __syncthreads();
    for (int off = 128; off > 0; off >>= 1) {
        if (tid < off) red[tid] = fmaxf(red[tid], red[tid + off]);
        __syncthreads();
    }
    mx = red[0];
    __syncthreads();

    float p[8];
    float sum = 0.f;
#pragma unroll
    for (int j = 0; j < 8; ++j) {
        p[j] = __expf(v[j] - mx);   // masked -> exp(~-1e9) == 0 exactly
        sum += p[j];
    }
    red[tid] = sum;
    __syncthreads();
    for (int off = 128; off > 0; off >>= 1) {
        if (tid < off) red[tid] += red[tid + off];
        __syncthreads();
    }
    float inv = 1.f / red[0];
#pragma unroll
    for (int j = 0; j < 8; ++j)
        row[tid + j * 256] = p[j] * inv;
}

// ---------------------------------------------------------------------------
// K3: attn[b][e] = sum_t probs[b][t] * enc[b][t][e]   (memory bound)
// ---------------------------------------------------------------------------
__global__ __launch_bounds__(256) void attn_kernel(const float* __restrict__ enc,
                                                   const float* __restrict__ probs,
                                                   float* __restrict__ attn) {
    __shared__ float pr[128];
    const int b = blockIdx.y;
    const int tc = blockIdx.x;        // 0..15  t-chunk of 128
    const int tid = threadIdx.x;
    if (tid < 128) pr[tid] = probs[b * Tt + tc * 128 + tid];
    __syncthreads();

    const int e0 = tid * 4;
    f32x4 acc; acc.x = 0.f; acc.y = 0.f; acc.z = 0.f; acc.w = 0.f;
    const float* base = enc + (size_t)b * Tt * Ee + (size_t)tc * 128 * Ee + e0;
#pragma unroll 4
    for (int t = 0; t < 128; ++t) {
        f32x4 vv = *reinterpret_cast<const f32x4*>(base + (size_t)t * Ee);
        float pw = pr[t];
        acc.x += pw * vv.x; acc.y += pw * vv.y;
        acc.z += pw * vv.z; acc.w += pw * vv.w;
    }
    atomicAdd(&attn[b * Ee + e0 + 0], acc.x);
    atomicAdd(&attn[b * Ee + e0 + 1], acc.y);
    atomicAdd(&attn[b * Ee + e0 + 2], acc.z);
    atomicAdd(&attn[b * Ee + e0 + 3], acc.w);
}

// ---------------------------------------------------------------------------
extern "C" void kernel_launch(void* const* d_in, const int* in_sizes, int n_in,
                              void* d_out, int out_size, void* d_ws, size_t ws_size,
                              hipStream_t stream) {
    const float* enc      = (const float*)d_in[0];
    const float* dec      = (const float*)d_in[1];
    const int*   inp_mask = (const int*)d_in[2];
    const float* W_enc    = (const float*)d_in[3];
    const float* b_enc    = (const float*)d_in[4];
    const float* W_dec    = (const float*)d_in[5];
    const float* b_dec    = (const float*)d_in[6];
    const float* W_out    = (const float*)d_in[7];
    // b_out (d_in[8]) cancels in softmax and is otherwise unused.

    float* attn   = (float*)d_out;            // [64][1024]
    float* scores = (float*)d_out + ATTN_N;   // [64][2048], becomes probs

    unsigned short* w16t = (unsigned short*)d_ws;  // 2 MB bf16 W_enc^T
    // ddec [64][1024] fp32 lives temporarily in the attn region of d_out;
    // it is consumed by gemm_score_kernel, then the region is zeroed for K3.
    float* ddec = attn;

    // zero score accumulator
    hipMemsetAsync(scores, 0, (size_t)PROB_N * sizeof(float), stream);

    wtrans_kernel<<<dim3(1024), 256, 0, stream>>>(W_enc, w16t);
    ddec_kernel<<<dim3(4, 64), 256, 0, stream>>>(dec, W_dec, b_dec, b_enc, ddec);
    gemm_score_kernel<<<dim3(4096), 512, 0, stream>>>(enc, w16t, ddec, W_out, scores);

    // attn region done serving as ddec; zero it for atomic accumulation
    hipMemsetAsync(attn, 0, (size_t)ATTN_N * sizeof(float), stream);

    softmax_kernel<<<dim3(64), 256, 0, stream>>>(scores, inp_mask);
    attn_kernel<<<dim3(16, 64), 256, 0, stream>>>(enc, scores, attn);
}

// Round 4
// 645.665 us; speedup vs baseline: 1.2364x; 1.0460x over previous
//
#include <hip/hip_runtime.h>
#include <hip/hip_bf16.h>

typedef __attribute__((ext_vector_type(4))) float f32x4;
typedef __attribute__((ext_vector_type(4))) unsigned int u32x4;
typedef __attribute__((ext_vector_type(2))) unsigned int u32x2;

// Problem constants
static constexpr int Bb = 64;
static constexpr int Tt = 2048;
static constexpr int Ee = 1024;
static constexpr int Hh = 1024;
static constexpr int ATTN_N = Bb * Ee;      // 65536
static constexpr int PROB_N = Bb * Tt;      // 131072

__device__ inline unsigned short f2bf(float f) {
    __hip_bfloat16 h = __float2bfloat16(f);  // RNE
    return __builtin_bit_cast(unsigned short, h);
}

// ---------------------------------------------------------------------------
// K0a: W_enc [E][H] fp32  ->  W16T [H][E] bf16 (transposed so GEMM B-frags are
// k-contiguous in LDS)
// ---------------------------------------------------------------------------
__global__ void wtrans_kernel(const float* __restrict__ w_enc,
                              unsigned short* __restrict__ w16t) {
    __shared__ float tile[32][33];
    const int bx = blockIdx.x & 31;   // h tile
    const int by = blockIdx.x >> 5;   // e tile
    const int tx = threadIdx.x & 31;
    const int ty = threadIdx.x >> 5;  // 0..7
#pragma unroll
    for (int j = 0; j < 4; ++j) {
        int e = by * 32 + ty + j * 8;
        int h = bx * 32 + tx;
        tile[ty + j * 8][tx] = w_enc[e * Hh + h];
    }
    __syncthreads();
#pragma unroll
    for (int j = 0; j < 4; ++j) {
        int h = bx * 32 + ty + j * 8;
        int e = by * 32 + tx;
        w16t[h * Ee + e] = f2bf(tile[tx][ty + j * 8]);
    }
}

// ---------------------------------------------------------------------------
// K0b: ddec[b][h] = dec[b]·W_dec[:,h] + b_dec[h] + b_enc[h]   (fp32 exact)
// ---------------------------------------------------------------------------
__global__ void ddec_kernel(const float* __restrict__ dec,
                            const float* __restrict__ w_dec,
                            const float* __restrict__ b_dec,
                            const float* __restrict__ b_enc,
                            float* __restrict__ ddec) {
    const int b = blockIdx.y;
    const int h = blockIdx.x * 256 + threadIdx.x;
    float acc = b_dec[h] + b_enc[h];
    const float* dr = dec + b * Ee;
#pragma unroll 4
    for (int e = 0; e < Ee; ++e) {
        acc += dr[e] * w_dec[e * Hh + h];
    }
    ddec[b * Hh + h] = acc;
}

// ---------------------------------------------------------------------------
// K1: fused  scores[b,t] += sum_h tanh(enc·W_enc + ddec) * W_out[h]
// 128x256 tile, BK=64, 8 waves (2M x 4N, each 64x64), mfma_f32_16x16x32_bf16.
// SCHEDULE (this round): LDS double-buffer + ONE raw s_barrier per K-step.
//  - regs hold tile t+1's global data across the barrier (reg-staged; A is
//    fp32->bf16 converted during ds_write)
//  - ds_writes for t+1 and global-load issue for t+2 sit BETWEEN the two
//    16-MFMA half-clusters, overlapping the matrix pipe
//  - raw __builtin_amdgcn_s_barrier() + manual s_waitcnt lgkmcnt(0): global
//    loads stay in flight across the barrier (no vmcnt(0) drain)
// XOR-swizzled LDS (conflict-free ds_read_b128) and XCD-aware block swizzle
// carried over unchanged from the verified R3 kernel.
// ---------------------------------------------------------------------------
__global__ __launch_bounds__(512, 2) void gemm_score_kernel(
    const float* __restrict__ enc, const unsigned short* __restrict__ w16t,
    const float* __restrict__ ddec, const float* __restrict__ w_out,
    float* __restrict__ scores) {
    __shared__ unsigned short As[2][128 * 64];
    __shared__ unsigned short Bs[2][256 * 64];

    const int tid = threadIdx.x;
    const int lane = tid & 63;
    const int wid = tid >> 6;          // 0..7
    const int wm = wid >> 2;           // 0..1
    const int wn = wid & 3;            // 0..3
    const int lr = lane & 15;
    const int lg = lane >> 4;          // 0..3

    // XCD-aware swizzle (8 XCDs, round-robin b->XCD b%8).
    const int g = blockIdx.x;
    const int xcd = g & 7;
    const int slot = g >> 3;           // 0..511
    const int ntile = slot & 3;        // 0..3
    const int mtile = xcd * 128 + (slot >> 2);  // 0..1023
    const int m0 = mtile * 128;
    const int n0 = ntile * 256;
    const int bidx = m0 >> 11;         // /T : whole tile in one batch row

    // staging maps (512 threads)
    const int arow = tid >> 4;          // 0..31 (+32*ci, 4 chunks)
    const int acol = (tid & 15) * 4;    // float4 column
    const int brow = tid >> 3;          // 0..63 (+64*ci, 4 chunks)
    const int bcol = (tid & 7) * 8;     // 8 bf16 (16B) chunk

    f32x4 areg[4];
    u32x4 breg[4];

    auto loadA = [&](int kt) {
        const float* src = enc + (size_t)m0 * Ee + kt * 64 + acol;
#pragma unroll
        for (int ci = 0; ci < 4; ++ci)
            areg[ci] = *reinterpret_cast<const f32x4*>(src + (size_t)(arow + 32 * ci) * Ee);
    };
    auto loadB = [&](int kt) {
        const unsigned short* src = w16t + (size_t)n0 * Ee + kt * 64 + bcol;
#pragma unroll
        for (int ci = 0; ci < 4; ++ci)
            breg[ci] = *reinterpret_cast<const u32x4*>(src + (size_t)(brow + 64 * ci) * Ee);
    };
    auto storeA = [&](int db) {
        char* base = (char*)&As[db][0];
#pragma unroll
        for (int ci = 0; ci < 4; ++ci) {
            int r = arow + 32 * ci;
            int off = r * 128 + ((acol * 2) ^ ((r & 7) << 4));
            unsigned int lo = (unsigned)f2bf(areg[ci].x) | ((unsigned)f2bf(areg[ci].y) << 16);
            unsigned int hi = (unsigned)f2bf(areg[ci].z) | ((unsigned)f2bf(areg[ci].w) << 16);
            u32x2 w; w.x = lo; w.y = hi;
            *reinterpret_cast<u32x2*>(base + off) = w;
        }
    };
    auto storeB = [&](int db) {
        char* base = (char*)&Bs[db][0];
#pragma unroll
        for (int ci = 0; ci < 4; ++ci) {
            int r = brow + 64 * ci;
            int off = r * 128 + ((bcol * 2) ^ ((r & 7) << 4));
            *reinterpret_cast<u32x4*>(base + off) = breg[ci];
        }
    };

    // accumulators init with ddec (same value for every row of a column)
    f32x4 acc[4][4];
#pragma unroll
    for (int ni = 0; ni < 4; ++ni) {
        float dv = ddec[bidx * Hh + n0 + wn * 64 + ni * 16 + lr];
#pragma unroll
        for (int mi = 0; mi < 4; ++mi) {
            acc[mi][ni].x = dv; acc[mi][ni].y = dv;
            acc[mi][ni].z = dv; acc[mi][ni].w = dv;
        }
    }

    // half-K-step MFMA cluster: frag reads (8+... b128) + 16 MFMA
    auto mfma_half = [&](int db, int kh) {
        const int kb = (kh * 32 + 8 * lg) * 2;   // byte offset of k-chunk
        const char* abase = (const char*)&As[db][0];
        const char* bbase = (const char*)&Bs[db][0];
        u32x4 af[4], bf[4];
#pragma unroll
        for (int mi = 0; mi < 4; ++mi) {
            int r = wm * 64 + mi * 16 + lr;
            af[mi] = *reinterpret_cast<const u32x4*>(abase + r * 128 + (kb ^ ((r & 7) << 4)));
        }
#pragma unroll
        for (int ni = 0; ni < 4; ++ni) {
            int r = wn * 64 + ni * 16 + lr;
            bf[ni] = *reinterpret_cast<const u32x4*>(bbase + r * 128 + (kb ^ ((r & 7) << 4)));
        }
        __builtin_amdgcn_s_setprio(1);
#pragma unroll
        for (int mi = 0; mi < 4; ++mi)
#pragma unroll
            for (int ni = 0; ni < 4; ++ni)
                asm("v_mfma_f32_16x16x32_bf16 %0, %1, %2, %0"
                    : "+v"(acc[mi][ni])
                    : "v"(af[mi]), "v"(bf[ni]));
        __builtin_amdgcn_s_setprio(0);
    };

    // ---- prologue: stage tile 0 into buf 0, prefetch tile 1 into regs ----
    loadA(0);
    loadB(0);
    storeA(0);
    storeB(0);
    loadA(1);
    loadB(1);
    asm volatile("s_waitcnt lgkmcnt(0)" ::: "memory");
    __builtin_amdgcn_s_barrier();
    asm volatile("" ::: "memory");

    int db = 0;
    for (int kt = 0; kt < Ee / 64; ++kt) {
        mfma_half(db, 0);
        // stage tile kt+1 into the other buffer; issue loads for kt+2.
        // These overlap the MFMA clusters on the other waves / same wave tail.
        if (kt < Ee / 64 - 1) {
            storeA(db ^ 1);
            storeB(db ^ 1);
        }
        if (kt < Ee / 64 - 2) {
            loadA(kt + 2);
            loadB(kt + 2);
        }
        mfma_half(db, 1);
        asm volatile("s_waitcnt lgkmcnt(0)" ::: "memory");
        __builtin_amdgcn_s_barrier();
        asm volatile("" ::: "memory");
        db ^= 1;
    }

    // drain MFMA pipe before VALU reads of acc
    asm volatile("s_nop 7\n\ts_nop 7\n\ts_nop 7" ::: );

    float wout[4];
#pragma unroll
    for (int ni = 0; ni < 4; ++ni)
        wout[ni] = w_out[n0 + wn * 64 + ni * 16 + lr];

#pragma unroll
    for (int mi = 0; mi < 4; ++mi) {
#pragma unroll
        for (int i = 0; i < 4; ++i) {
            float s = 0.f;
#pragma unroll
            for (int ni = 0; ni < 4; ++ni) {
                float x = (i == 0) ? acc[mi][ni].x : (i == 1) ? acc[mi][ni].y
                           : (i == 2) ? acc[mi][ni].z : acc[mi][ni].w;
                // tanh(x) = 1 - 2/(e^{2x}+1)  (stable at +/-inf)
                float t = 1.f - 2.f / (__expf(2.f * x) + 1.f);
                s += t * wout[ni];
            }
            s += __shfl_xor(s, 1);
            s += __shfl_xor(s, 2);
            s += __shfl_xor(s, 4);
            s += __shfl_xor(s, 8);
            if (lr == 0) {
                int row = m0 + wm * 64 + mi * 16 + 4 * lg + i;
                atomicAdd(&scores[row], s);
            }
        }
    }
}

// ---------------------------------------------------------------------------
// K2: masked softmax over T per batch row, in place (scores -> probs).
// b_out cancels in softmax so it is never added.
// ---------------------------------------------------------------------------
__global__ __launch_bounds__(256) void softmax_kernel(float* __restrict__ sc,
                                                      const int* __restrict__ mask) {
    __shared__ float red[256];
    const int b = blockIdx.x;
    const int tid = threadIdx.x;
    float* row = sc + b * Tt;
    const int* mrow = mask + b * Tt;

    float v[8];
    float mx = -3.0e38f;
#pragma unroll
    for (int j = 0; j < 8; ++j) {
        int t = tid + j * 256;
        float s = row[t];
        v[j] = (mrow[t] == 0) ? -1.0e9f : s;
        mx = fmaxf(mx, v[j]);
    }
    red[tid] = mx;
    __syncthreads();
    for (int off = 128; off > 0; off >>= 1) {
        if (tid < off) red[tid] = fmaxf(red[tid], red[tid + off]);
        __syncthreads();
    }
    mx = red[0];
    __syncthreads();

    float p[8];
    float sum = 0.f;
#pragma unroll
    for (int j = 0; j < 8; ++j) {
        p[j] = __expf(v[j] - mx);   // masked -> exp(~-1e9) == 0 exactly
        sum += p[j];
    }
    red[tid] = sum;
    __syncthreads();
    for (int off = 128; off > 0; off >>= 1) {
        if (tid < off) red[tid] += red[tid + off];
        __syncthreads();
    }
    float inv = 1.f / red[0];
#pragma unroll
    for (int j = 0; j < 8; ++j)
        row[tid + j * 256] = p[j] * inv;
}

// ---------------------------------------------------------------------------
// K3: attn[b][e] = sum_t probs[b][t] * enc[b][t][e]   (memory bound)
// ---------------------------------------------------------------------------
__global__ __launch_bounds__(256) void attn_kernel(const float* __restrict__ enc,
                                                   const float* __restrict__ probs,
                                                   float* __restrict__ attn) {
    __shared__ float pr[128];
    const int b = blockIdx.y;
    const int tc = blockIdx.x;        // 0..15  t-chunk of 128
    const int tid = threadIdx.x;
    if (tid < 128) pr[tid] = probs[b * Tt + tc * 128 + tid];
    __syncthreads();

    const int e0 = tid * 4;
    f32x4 acc; acc.x = 0.f; acc.y = 0.f; acc.z = 0.f; acc.w = 0.f;
    const float* base = enc + (size_t)b * Tt * Ee + (size_t)tc * 128 * Ee + e0;
#pragma unroll 4
    for (int t = 0; t < 128; ++t) {
        f32x4 vv = *reinterpret_cast<const f32x4*>(base + (size_t)t * Ee);
        float pw = pr[t];
        acc.x += pw * vv.x; acc.y += pw * vv.y;
        acc.z += pw * vv.z; acc.w += pw * vv.w;
    }
    atomicAdd(&attn[b * Ee + e0 + 0], acc.x);
    atomicAdd(&attn[b * Ee + e0 + 1], acc.y);
    atomicAdd(&attn[b * Ee + e0 + 2], acc.z);
    atomicAdd(&attn[b * Ee + e0 + 3], acc.w);
}

// ---------------------------------------------------------------------------
extern "C" void kernel_launch(void* const* d_in, const int* in_sizes, int n_in,
                              void* d_out, int out_size, void* d_ws, size_t ws_size,
                              hipStream_t stream) {
    const float* enc      = (const float*)d_in[0];
    const float* dec      = (const float*)d_in[1];
    const int*   inp_mask = (const int*)d_in[2];
    const float* W_enc    = (const float*)d_in[3];
    const float* b_enc    = (const float*)d_in[4];
    const float* W_dec    = (const float*)d_in[5];
    const float* b_dec    = (const float*)d_in[6];
    const float* W_out    = (const float*)d_in[7];
    // b_out (d_in[8]) cancels in softmax and is otherwise unused.

    float* attn   = (float*)d_out;            // [64][1024]
    float* scores = (float*)d_out + ATTN_N;   // [64][2048], becomes probs

    unsigned short* w16t = (unsigned short*)d_ws;  // 2 MB bf16 W_enc^T
    // ddec [64][1024] fp32 lives temporarily in the attn region of d_out;
    // it is consumed by gemm_score_kernel, then the region is zeroed for K3.
    float* ddec = attn;

    // zero score accumulator
    hipMemsetAsync(scores, 0, (size_t)PROB_N * sizeof(float), stream);

    wtrans_kernel<<<dim3(1024), 256, 0, stream>>>(W_enc, w16t);
    ddec_kernel<<<dim3(4, 64), 256, 0, stream>>>(dec, W_dec, b_dec, b_enc, ddec);
    gemm_score_kernel<<<dim3(4096), 512, 0, stream>>>(enc, w16t, ddec, W_out, scores);

    // attn region done serving as ddec; zero it for atomic accumulation
    hipMemsetAsync(attn, 0, (size_t)ATTN_N * sizeof(float), stream);

    softmax_kernel<<<dim3(64), 256, 0, stream>>>(scores, inp_mask);
    attn_kernel<<<dim3(16, 64), 256, 0, stream>>>(enc, scores, attn);
}